// Round 6
// baseline (231.826 us; speedup 1.0000x reference)
//
#include <hip/hip_runtime.h>
#include <math.h>

// LightConv1d: B=8, C=1024, T=4096, H=16, K=7, causal pad L=6.
// out[b,c,t] = sum_k softmax(w)[c%16,k] * x[b,c,t-6+k] + bias[c%16]
//
// Single fused kernel, 8 outputs (one 32 B oct) per thread.
//  - out_size is a FLOAT COUNT (verified: R0/R1's out_size/4 float4 grid
//    passed with absmax 0.0078) -> octs = out_size/8.
//  - h = row & 15 is block-uniform, so the 7-tap softmax is recomputed
//    inline per thread (~35 VALU ops, hidden under VMEM wait). No
//    workspace, no 2nd dispatch.
//  - 2-quad tile: 4 loads + 2 stores per 32 B out (vs 6+2 for the 4/thread
//    version) -> 25% fewer VMEM instructions, 33% less L1 halo re-read.
//  - Accumulate into float o[8], then form the two f4 stores explicitly
//    (no per-iteration conditional vector-element writes).
//  - Non-temporal stores: out is write-once; don't evict x halo lines.
#define TT 4096
#define KK 7
#define HH 16

typedef float f4 __attribute__((ext_vector_type(4)));

__global__ __launch_bounds__(256) void lightconv_fused(
    const float* __restrict__ x, const float* __restrict__ w,
    const float* __restrict__ bias, float* __restrict__ out) {
    const int O   = blockIdx.x * 256 + threadIdx.x;  // global oct (8-float) index
    const int row = O >> 9;         // b*C + c   (T/8 = 512 octs per row)
    const int to  = O & 511;        // oct within row
    const int h   = row & (HH - 1); // block-uniform

    // Inline softmax over this head's 7 taps (scalar-broadcast loads).
    float v[KK];
    float m = -1e30f;
    #pragma unroll
    for (int k = 0; k < KK; ++k) { v[k] = w[h * KK + k]; m = fmaxf(m, v[k]); }
    float s = 0.f;
    #pragma unroll
    for (int k = 0; k < KK; ++k) { v[k] = __expf(v[k] - m); s += v[k]; }
    const float inv = 1.f / s;
    const float w0 = v[0] * inv, w1 = v[1] * inv, w2 = v[2] * inv,
                w3 = v[3] * inv, w4 = v[4] * inv, w5 = v[5] * inv,
                w6 = v[6] * inv;
    const float bb = bias[h];

    // Row has 1024 quads; this thread's oct = quads {2*to, 2*to+1}.
    const f4* xr = (const f4*)(x + (size_t)row * TT);
    const int q = to * 2;
    f4 q2 = xr[q];                          // x[t0   .. t0+3]
    f4 q3 = xr[q + 1];                      // x[t0+4 .. t0+7]
    f4 q1 = (f4){0.f, 0.f, 0.f, 0.f};
    f4 q0 = (f4){0.f, 0.f, 0.f, 0.f};
    if (to >= 1) {                          // only the oct-0 lane skips
        q1 = xr[q - 1];                     // x[t0-4 .. t0-1]
        q0 = xr[q - 2];                     // x[t0-8 .. t0-5]
    }

    // f[i] = x[t0 - 8 + i], i=0..15; out[t0+j] = sum_k w[k]*f[j+k+2], j=0..7
    float f[16] = {q0.x, q0.y, q0.z, q0.w,
                   q1.x, q1.y, q1.z, q1.w,
                   q2.x, q2.y, q2.z, q2.w,
                   q3.x, q3.y, q3.z, q3.w};

    float o[8];
    #pragma unroll
    for (int j = 0; j < 8; ++j) {
        float acc = bb;
        acc = fmaf(w0, f[j + 2], acc);
        acc = fmaf(w1, f[j + 3], acc);
        acc = fmaf(w2, f[j + 4], acc);
        acc = fmaf(w3, f[j + 5], acc);
        acc = fmaf(w4, f[j + 6], acc);
        acc = fmaf(w5, f[j + 7], acc);
        acc = fmaf(w6, f[j + 8], acc);
        o[j] = acc;
    }
    const f4 oa = (f4){o[0], o[1], o[2], o[3]};
    const f4 ob = (f4){o[4], o[5], o[6], o[7]};
    f4* orow = (f4*)(out + (size_t)row * TT);
    __builtin_nontemporal_store(oa, orow + q);
    __builtin_nontemporal_store(ob, orow + q + 1);
}

extern "C" void kernel_launch(void* const* d_in, const int* in_sizes, int n_in,
                              void* d_out, int out_size, void* d_ws, size_t ws_size,
                              hipStream_t stream) {
    const float* x    = (const float*)d_in[0];
    const float* w    = (const float*)d_in[1];
    const float* bias = (const float*)d_in[2];
    float* out = (float*)d_out;
    (void)d_ws; (void)ws_size;

    const int totalO = out_size / 8;  // out_size = float count; 4,194,304 octs
    lightconv_fused<<<totalO / 256, 256, 0, stream>>>(x, w, bias, out);
}

// Round 7
// 222.548 us; speedup vs baseline: 1.0417x; 1.0417x over previous
//
#include <hip/hip_runtime.h>
#include <math.h>

// LightConv1d: B=8, C=1024, T=4096, H=16, K=7, causal pad L=6.
// out[b,c,t] = sum_k softmax(w)[c%16,k] * x[b,c,t-6+k] + bias[c%16]
//
// FINAL (revert to R1/R5 body, verified 225.97/226.73 us):
// Single fused kernel, 4 outputs (one float4 quad) per thread.
//  - h = (b*C+c) & 15 is BLOCK-uniform -> 7-tap softmax recomputed inline
//    per thread (~35 VALU ops, hidden under VMEM wait; VALUBusy single-
//    digit). No workspace, no 2nd dispatch (R0->R1: -3.8 us).
//  - 8-outputs-per-thread variant measured WORSE (231.8 us, R6): conv is
//    purely HBM-BW-bound; halving thread count reduced latency hiding.
//  - Conv slice ~46 us for 268 MB traffic = 5.8 TB/s = 92% of achievable
//    ceiling; remaining dur_us is harness poison fills (~180 us).
#define TT 4096
#define KK 7
#define HH 16

typedef float f4 __attribute__((ext_vector_type(4)));

__global__ __launch_bounds__(256) void lightconv_fused(
    const float* __restrict__ x, const float* __restrict__ w,
    const float* __restrict__ bias, float* __restrict__ out) {
    const int Q   = blockIdx.x * 256 + threadIdx.x;  // global quad index
    const int row = Q >> 10;        // b*C + c   (T/4 = 1024 quads per row)
    const int tq  = Q & 1023;       // quad within row
    const int h   = row & (HH - 1); // block-uniform

    // Inline softmax over this head's 7 taps. __expf -> v_exp_f32 (+scale),
    // ~1e-6 relative error on weights that sum to 1 — far inside tolerance.
    float v[KK];
    float m = -1e30f;
    #pragma unroll
    for (int k = 0; k < KK; ++k) { v[k] = w[h * KK + k]; m = fmaxf(m, v[k]); }
    float s = 0.f;
    #pragma unroll
    for (int k = 0; k < KK; ++k) { v[k] = __expf(v[k] - m); s += v[k]; }
    const float inv = 1.f / s;
    const float w0 = v[0] * inv, w1 = v[1] * inv, w2 = v[2] * inv,
                w3 = v[3] * inv, w4 = v[4] * inv, w5 = v[5] * inv,
                w6 = v[6] * inv;
    const float bb = bias[h];

    // x loads stay cached (halo quads are re-read by neighbor threads/blocks
    // out of L1/L2 — do NOT mark these non-temporal).
    const f4* xr = (const f4*)(x + (size_t)row * TT);
    f4 q2 = xr[tq];                         // x[t0 .. t0+3]
    f4 q1 = (f4){0.f, 0.f, 0.f, 0.f};
    f4 q0 = (f4){0.f, 0.f, 0.f, 0.f};
    if (tq >= 1) q1 = xr[tq - 1];           // x[t0-4 .. t0-1]
    if (tq >= 2) q0 = xr[tq - 2];           // x[t0-8 .. t0-5]

    // f[i] = x[t0 - 8 + i]; out[t0+j] = sum_k w[k]*f[j+k+2]
    float f[12] = {q0.x, q0.y, q0.z, q0.w,
                   q1.x, q1.y, q1.z, q1.w,
                   q2.x, q2.y, q2.z, q2.w};

    f4 o;
    #pragma unroll
    for (int j = 0; j < 4; ++j) {
        float acc = bb;
        acc = fmaf(w0, f[j + 2], acc);
        acc = fmaf(w1, f[j + 3], acc);
        acc = fmaf(w2, f[j + 4], acc);
        acc = fmaf(w3, f[j + 5], acc);
        acc = fmaf(w4, f[j + 6], acc);
        acc = fmaf(w5, f[j + 7], acc);
        acc = fmaf(w6, f[j + 8], acc);
        o[j] = acc;
    }
    // out is write-once and never re-read by this kernel: non-temporal store
    // keeps stores from evicting x halo lines out of L2.
    __builtin_nontemporal_store(o, ((f4*)(out + (size_t)row * TT)) + tq);
}

extern "C" void kernel_launch(void* const* d_in, const int* in_sizes, int n_in,
                              void* d_out, int out_size, void* d_ws, size_t ws_size,
                              hipStream_t stream) {
    const float* x    = (const float*)d_in[0];
    const float* w    = (const float*)d_in[1];
    const float* bias = (const float*)d_in[2];
    float* out = (float*)d_out;
    (void)d_ws; (void)ws_size;

    const int totalQ = out_size / 4;  // out_size = float count; 8,388,608 float4s
    lightconv_fused<<<totalQ / 256, 256, 0, stream>>>(x, w, bias, out);
}